// Round 1
// baseline (140.427 us; speedup 1.0000x reference)
//
#include <hip/hip_runtime.h>
#include <hip/hip_bf16.h>

typedef float f32x4 __attribute__((ext_vector_type(4)));
typedef __bf16 bf16x8 __attribute__((ext_vector_type(8)));
typedef unsigned short u16;

// Problem dims (fixed): B=128, T=64, H=1024, Hu=512, J=129, N=128, I=64, MJW=64
// ws layout
#define OFF_W1T  0u            // 512x1024 bf16 = 1048576 B  (W1T[n][k] = W1[k][n])
#define OFF_W23T 1048576u      // 144x512  bf16 = 147456 B   (rows 0..128 = W2 cols, 129 = W3, 130..143 = 0)
#define OFF_TS   1196032u      // 8192x512 bf16 = 8388608 B
#define OFF_JW   9584640u      // 8192x132 f32  = 4325376 B
#define OFF_P0   13910016u     // 8192 f32 = 32768 B

static __device__ __forceinline__ u16 f2bf(float x) {
    __bf16 h = (__bf16)x;
    return __builtin_bit_cast(u16, h);
}

__global__ void prep_kernel(const float* __restrict__ W1, const float* __restrict__ W2,
                            const float* __restrict__ W3,
                            __bf16* __restrict__ W1T, __bf16* __restrict__ W23T)
{
    int idx = blockIdx.x * 256 + threadIdx.x;
    const int total = 524288 + 73728;
    for (; idx < total; idx += gridDim.x * 256) {
        if (idx < 524288) {
            int n = idx >> 10, k = idx & 1023;
            W1T[idx] = (__bf16)W1[k * 512 + n];
        } else {
            int j = idx - 524288;
            int n = j >> 9, k = j & 511;
            float v = 0.0f;
            if (n < 129) v = W2[k * 129 + n];
            else if (n == 129) v = W3[k];
            W23T[j] = (__bf16)v;
        }
    }
}

// GEMM1: ts = tanh(Y[8192x1024] @ W1[1024x512] + b1), bf16 MFMA 16x16x32
// grid (64,4), 256 threads (4 waves), tile 128x128, BK=32, reg-staged LDS (pad 40)
__global__ __launch_bounds__(256) void gemm1_kernel(
    const float* __restrict__ Y, const __bf16* __restrict__ W1T,
    const float* __restrict__ b1, u16* __restrict__ ts)
{
    __shared__ __bf16 As[128][40];
    __shared__ __bf16 Bs[128][40];
    const int tid = threadIdx.x;
    const int m0 = blockIdx.x * 128, n0 = blockIdx.y * 128;
    const int wid = tid >> 6, lane = tid & 63;
    const int wr = wid >> 1, wc = wid & 1;
    const int lr = lane & 15, lg = lane >> 4;
    const int srow = tid >> 1, shalf = tid & 1;

    f32x4 acc[4][4];
    #pragma unroll
    for (int m = 0; m < 4; m++)
        #pragma unroll
        for (int n = 0; n < 4; n++) {
            f32x4 z = {0.f, 0.f, 0.f, 0.f};
            acc[m][n] = z;
        }

    const float* ya = Y + (size_t)(m0 + srow) * 1024 + shalf * 16;
    const __bf16* wb = W1T + (size_t)(n0 + srow) * 1024 + shalf * 16;

    for (int kt = 0; kt < 32; ++kt) {
        // stage A (f32 -> bf16)
        const float4* yp = (const float4*)(ya + kt * 32);
        float4 f0 = yp[0], f1 = yp[1], f2 = yp[2], f3 = yp[3];
        bf16x8 a0, a1;
        a0[0] = (__bf16)f0.x; a0[1] = (__bf16)f0.y; a0[2] = (__bf16)f0.z; a0[3] = (__bf16)f0.w;
        a0[4] = (__bf16)f1.x; a0[5] = (__bf16)f1.y; a0[6] = (__bf16)f1.z; a0[7] = (__bf16)f1.w;
        a1[0] = (__bf16)f2.x; a1[1] = (__bf16)f2.y; a1[2] = (__bf16)f2.z; a1[3] = (__bf16)f2.w;
        a1[4] = (__bf16)f3.x; a1[5] = (__bf16)f3.y; a1[6] = (__bf16)f3.z; a1[7] = (__bf16)f3.w;
        *(bf16x8*)&As[srow][shalf * 16]     = a0;
        *(bf16x8*)&As[srow][shalf * 16 + 8] = a1;
        // stage B (already bf16)
        const uint4* wp = (const uint4*)(wb + kt * 32);
        uint4 q0 = wp[0], q1 = wp[1];
        *(uint4*)&Bs[srow][shalf * 16]     = q0;
        *(uint4*)&Bs[srow][shalf * 16 + 8] = q1;
        __syncthreads();

        bf16x8 af[4], bfr[4];
        #pragma unroll
        for (int m = 0; m < 4; m++) af[m] = *(const bf16x8*)&As[wr * 64 + m * 16 + lr][lg * 8];
        #pragma unroll
        for (int n = 0; n < 4; n++) bfr[n] = *(const bf16x8*)&Bs[wc * 64 + n * 16 + lr][lg * 8];
        #pragma unroll
        for (int m = 0; m < 4; m++)
            #pragma unroll
            for (int n = 0; n < 4; n++)
                acc[m][n] = __builtin_amdgcn_mfma_f32_16x16x32_bf16(af[m], bfr[n], acc[m][n], 0, 0, 0);
        __syncthreads();
    }

    #pragma unroll
    for (int m = 0; m < 4; m++) {
        #pragma unroll
        for (int n = 0; n < 4; n++) {
            int col = n0 + wc * 64 + n * 16 + lr;
            float bias = b1[col];
            #pragma unroll
            for (int j = 0; j < 4; j++) {
                int row = m0 + wr * 64 + m * 16 + lg * 4 + j;
                float v = tanhf(acc[m][n][j] + bias);
                ts[(size_t)row * 512 + col] = f2bf(v);
            }
        }
    }
}

// GEMM2 + softmax + sigmoid: logits = ts[8192x512] @ W23T^T (130 cols, padded 144)
// one wave per 16 rows; 128 blocks x 256 threads
__global__ __launch_bounds__(256) void gemm2_kernel(
    const u16* __restrict__ ts, const u16* __restrict__ W23T,
    const float* __restrict__ b2, const float* __restrict__ b3,
    float* __restrict__ jw, float* __restrict__ p0)
{
    const int tid = threadIdx.x;
    const int wid = tid >> 6, lane = tid & 63;
    const int gw = blockIdx.x * 4 + wid;
    const int r0 = gw * 16;
    const int lr = lane & 15, lg = lane >> 4;

    f32x4 acc[9];
    #pragma unroll
    for (int ct = 0; ct < 9; ct++) { f32x4 z = {0.f,0.f,0.f,0.f}; acc[ct] = z; }

    for (int kk = 0; kk < 16; ++kk) {
        int k0 = kk * 32 + lg * 8;
        bf16x8 a = *(const bf16x8*)(ts + (size_t)(r0 + lr) * 512 + k0);
        #pragma unroll
        for (int ct = 0; ct < 9; ct++) {
            bf16x8 bv = *(const bf16x8*)(W23T + (size_t)(ct * 16 + lr) * 512 + k0);
            acc[ct] = __builtin_amdgcn_mfma_f32_16x16x32_bf16(a, bv, acc[ct], 0, 0, 0);
        }
    }

    float b3v = b3[0];
    #pragma unroll
    for (int j = 0; j < 4; j++) {
        int row = r0 + lg * 4 + j;
        float v[9];
        float mx = -1e30f;
        #pragma unroll
        for (int ct = 0; ct < 9; ct++) {
            int col = ct * 16 + lr;
            if (col < 129) { float x = acc[ct][j] + b2[col]; v[ct] = x; mx = fmaxf(mx, x); }
            else v[ct] = -1e30f;
        }
        #pragma unroll
        for (int o = 1; o < 16; o <<= 1) mx = fmaxf(mx, __shfl_xor(mx, o));
        float sum = 0.f;
        #pragma unroll
        for (int ct = 0; ct < 9; ct++) {
            int col = ct * 16 + lr;
            if (col < 129) { float e = expf(v[ct] - mx); v[ct] = e; sum += e; }
        }
        #pragma unroll
        for (int o = 1; o < 16; o <<= 1) sum += __shfl_xor(sum, o);
        float inv = 1.0f / sum;
        #pragma unroll
        for (int ct = 0; ct < 9; ct++) {
            int col = ct * 16 + lr;
            if (col < 129) jw[(size_t)row * 132 + col] = v[ct] * inv;
        }
        if (lr == 1) {  // col 129 = p0 logit
            float pv = acc[8][j] + b3v;
            p0[row] = 1.0f / (1.0f + expf(-pv));
        }
    }
}

// Recurrence: one block per batch, 128 threads.
__global__ __launch_bounds__(128) void recur_kernel(
    const float* __restrict__ jw, const float* __restrict__ p0g,
    const float* __restrict__ em, const int* __restrict__ slen,
    float* __restrict__ out)
{
    __shared__ float jw_s[64 * 132];
    __shared__ float em_s[128][65];
    __shared__ float p0_s[64];
    __shared__ float atil[64];
    __shared__ float part[2][64];
    __shared__ float u_s[128];
    __shared__ float wsum[2];
    const int b = blockIdx.x, t = threadIdx.x;

    const float4* jg = (const float4*)(jw + (size_t)b * 64 * 132);
    float4* js4 = (float4*)jw_s;
    for (int i = t; i < 2112; i += 128) js4[i] = jg[i];
    const float4* eg = (const float4*)(em + (size_t)b * 8192);
    for (int i4 = t; i4 < 2048; i4 += 128) {
        float4 v = eg[i4];
        int base = i4 * 4; int n = base >> 6; int ii = base & 63;
        em_s[n][ii] = v.x; em_s[n][ii + 1] = v.y; em_s[n][ii + 2] = v.z; em_s[n][ii + 3] = v.w;
    }
    if (t < 64) p0_s[t] = p0g[b * 64 + t];
    __syncthreads();
    if (t < 64) atil[t] = em_s[t][0] + em_s[t + 64][0];
    const int idx = slen[b] - 1;
    float L = 1.0f;
    __syncthreads();

    for (int i = 1; i <= idx; ++i) {
        const int c = t & 63, h = t >> 6;
        float s0 = 0.f, s1 = 0.f, s2 = 0.f, s3 = 0.f;
        #pragma unroll
        for (int q = 0; q < 32; q += 4) {
            int it = h * 32 + q;
            s0 = fmaf(atil[it],     jw_s[it * 132       + 64 + c - it], s0);
            s1 = fmaf(atil[it + 1], jw_s[(it + 1) * 132 + 63 + c - it], s1);
            s2 = fmaf(atil[it + 2], jw_s[(it + 2) * 132 + 62 + c - it], s2);
            s3 = fmaf(atil[it + 3], jw_s[(it + 3) * 132 + 61 + c - it], s3);
        }
        part[h][c] = (s0 + s1) + (s2 + s3);
        __syncthreads();
        float u;
        if (t < 64) u = (part[0][t] + part[1][t]) * em_s[t][i];
        else        u = atil[c] * p0_s[c] * em_s[t][i];
        u_s[t] = u;
        float r = u;
        #pragma unroll
        for (int o = 32; o > 0; o >>= 1) r += __shfl_xor(r, o);
        if ((t & 63) == 0) wsum[t >> 6] = r;
        __syncthreads();
        float s = wsum[0] + wsum[1];
        L += logf(128.0f * s);
        if (t < 64) atil[t] = (u_s[t] + u_s[t + 64]) / s;
        __syncthreads();
    }
    if (t == 0) out[b] = L;
}

extern "C" void kernel_launch(void* const* d_in, const int* in_sizes, int n_in,
                              void* d_out, int out_size, void* d_ws, size_t ws_size,
                              hipStream_t stream)
{
    const float* Y   = (const float*)d_in[0];
    const float* em  = (const float*)d_in[1];
    const int*   sl  = (const int*)d_in[2];
    const float* W1  = (const float*)d_in[3];
    const float* b1  = (const float*)d_in[4];
    const float* W2  = (const float*)d_in[5];
    const float* b2  = (const float*)d_in[6];
    const float* W3  = (const float*)d_in[7];
    const float* b3  = (const float*)d_in[8];
    float* out = (float*)d_out;
    char* ws = (char*)d_ws;

    __bf16* W1T  = (__bf16*)(ws + OFF_W1T);
    __bf16* W23T = (__bf16*)(ws + OFF_W23T);
    u16*    ts   = (u16*)(ws + OFF_TS);
    float*  jw   = (float*)(ws + OFF_JW);
    float*  p0   = (float*)(ws + OFF_P0);

    prep_kernel<<<2336, 256, 0, stream>>>(W1, W2, W3, W1T, W23T);
    dim3 g1(64, 4);
    gemm1_kernel<<<g1, 256, 0, stream>>>(Y, W1T, b1, ts);
    gemm2_kernel<<<128, 256, 0, stream>>>(ts, (const u16*)W23T, b2, b3, jw, p0);
    recur_kernel<<<128, 128, 0, stream>>>(jw, p0, em, sl, out);
}

// Round 2
// 97.729 us; speedup vs baseline: 1.4369x; 1.4369x over previous
//
#include <hip/hip_runtime.h>
#include <hip/hip_bf16.h>

typedef float f32x4 __attribute__((ext_vector_type(4)));
typedef __bf16 bf16x8 __attribute__((ext_vector_type(8)));
typedef unsigned short u16;

// Problem dims (fixed): B=128, T=64, H=1024, Hu=512, J=129, N=128, I=64, MJW=64
// ws layout
#define OFF_W1T  0u            // 512x1024 bf16 = 1048576 B  (W1T[n][k] = W1[k][n])
#define OFF_W23T 1048576u      // 144x512  bf16 = 147456 B   (rows 0..128 = W2 cols, 129 = W3, 130..143 = 0)
#define OFF_TS   1196032u      // 8192x512 bf16 = 8388608 B
#define OFF_JW   9584640u      // 8192x132 f32  = 4325376 B
#define OFF_P0   13910016u     // 8192 f32 = 32768 B

static __device__ __forceinline__ u16 f2bf(float x) {
    __bf16 h = (__bf16)x;
    return __builtin_bit_cast(u16, h);
}

__global__ void prep_kernel(const float* __restrict__ W1, const float* __restrict__ W2,
                            const float* __restrict__ W3,
                            __bf16* __restrict__ W1T, __bf16* __restrict__ W23T)
{
    int idx = blockIdx.x * 256 + threadIdx.x;
    const int total = 524288 + 73728;
    for (; idx < total; idx += gridDim.x * 256) {
        if (idx < 524288) {
            int n = idx >> 10, k = idx & 1023;
            W1T[idx] = (__bf16)W1[k * 512 + n];
        } else {
            int j = idx - 524288;
            int n = j >> 9, k = j & 511;
            float v = 0.0f;
            if (n < 129) v = W2[k * 129 + n];
            else if (n == 129) v = W3[k];
            W23T[j] = (__bf16)v;
        }
    }
}

// ---------------------------------------------------------------------------
// GEMM1: ts = tanh(Y[8192x1024] @ W1[1024x512] + b1), bf16 MFMA 16x16x32
// 128x128 tile, BK=64, 512 threads (8 waves, 2x4), double-buffered swizzled LDS,
// reg-staged prefetch (loads for t+1 in flight across the barrier of t).
// ---------------------------------------------------------------------------
struct Stage {
    float4 a0, a1, a2, a3;   // 16 f32 of Y
    uint4  b0, b1;           // 16 bf16 of W1T
};

__global__ __launch_bounds__(512) void gemm1_kernel(
    const float* __restrict__ Y, const __bf16* __restrict__ W1T,
    const float* __restrict__ b1, u16* __restrict__ ts)
{
    __shared__ __bf16 As[2][128 * 64];
    __shared__ __bf16 Bs[2][128 * 64];
    const int tid = threadIdx.x;
    const int m0 = blockIdx.x * 128, n0 = blockIdx.y * 128;
    const int wid = tid >> 6, lane = tid & 63;
    const int wr = wid >> 2, wc = wid & 3;          // 2 x 4 waves, wave tile 64x32
    const int lr = lane & 15, lg = lane >> 4;

    const int ra = tid >> 2;             // staging row 0..127
    const int kc = (tid & 3) * 16;       // staging k-chunk 0/16/32/48
    const int esw = ((ra & 7) << 3);     // XOR swizzle for this thread's stores
    const int e0 = kc ^ esw;
    const int e1 = (kc + 8) ^ esw;

    const float*  ya = Y   + (size_t)(m0 + ra) * 1024 + kc;
    const __bf16* wb = W1T + (size_t)(n0 + ra) * 1024 + kc;

    f32x4 acc[4][2];
    #pragma unroll
    for (int m = 0; m < 4; m++)
        #pragma unroll
        for (int n = 0; n < 2; n++) { f32x4 z = {0.f,0.f,0.f,0.f}; acc[m][n] = z; }

#define ISSUE(S, kt) do { \
    const float4* yp = (const float4*)(ya + (kt) * 64); \
    (S).a0 = yp[0]; (S).a1 = yp[1]; (S).a2 = yp[2]; (S).a3 = yp[3]; \
    const uint4* wp = (const uint4*)(wb + (kt) * 64); \
    (S).b0 = wp[0]; (S).b1 = wp[1]; \
} while (0)

#define WRITE(S, buf) do { \
    bf16x8 pa0, pa1; \
    pa0[0]=(__bf16)(S).a0.x; pa0[1]=(__bf16)(S).a0.y; pa0[2]=(__bf16)(S).a0.z; pa0[3]=(__bf16)(S).a0.w; \
    pa0[4]=(__bf16)(S).a1.x; pa0[5]=(__bf16)(S).a1.y; pa0[6]=(__bf16)(S).a1.z; pa0[7]=(__bf16)(S).a1.w; \
    pa1[0]=(__bf16)(S).a2.x; pa1[1]=(__bf16)(S).a2.y; pa1[2]=(__bf16)(S).a2.z; pa1[3]=(__bf16)(S).a2.w; \
    pa1[4]=(__bf16)(S).a3.x; pa1[5]=(__bf16)(S).a3.y; pa1[6]=(__bf16)(S).a3.z; pa1[7]=(__bf16)(S).a3.w; \
    *(bf16x8*)&As[buf][ra * 64 + e0] = pa0; \
    *(bf16x8*)&As[buf][ra * 64 + e1] = pa1; \
    *(uint4*)&Bs[buf][ra * 64 + e0] = (S).b0; \
    *(uint4*)&Bs[buf][ra * 64 + e1] = (S).b1; \
} while (0)

#define COMPUTE(buf) do { \
    const int swl = (lr & 7) << 3; \
    _Pragma("unroll") \
    for (int ks = 0; ks < 2; ++ks) { \
        const int eoff = (ks * 32 + lg * 8) ^ swl; \
        bf16x8 af[4], bfr[2]; \
        _Pragma("unroll") \
        for (int m = 0; m < 4; ++m) af[m] = *(const bf16x8*)&As[buf][(wr * 64 + m * 16 + lr) * 64 + eoff]; \
        _Pragma("unroll") \
        for (int n = 0; n < 2; ++n) bfr[n] = *(const bf16x8*)&Bs[buf][(wc * 32 + n * 16 + lr) * 64 + eoff]; \
        _Pragma("unroll") \
        for (int m = 0; m < 4; ++m) \
            _Pragma("unroll") \
            for (int n = 0; n < 2; ++n) \
                acc[m][n] = __builtin_amdgcn_mfma_f32_16x16x32_bf16(af[m], bfr[n], acc[m][n], 0, 0, 0); \
    } \
} while (0)

    Stage SA, SB;
    ISSUE(SA, 0);
    #pragma unroll 1
    for (int kt = 0; kt < 16; kt += 2) {
        ISSUE(SB, kt + 1);
        WRITE(SA, 0);
        __syncthreads();
        COMPUTE(0);
        if (kt + 2 < 16) ISSUE(SA, kt + 2);
        WRITE(SB, 1);
        __syncthreads();
        COMPUTE(1);
    }

    // epilogue: bias + tanh + bf16 store
    #pragma unroll
    for (int m = 0; m < 4; m++) {
        #pragma unroll
        for (int n = 0; n < 2; n++) {
            int col = n0 + wc * 32 + n * 16 + lr;
            float bias = b1[col];
            #pragma unroll
            for (int j = 0; j < 4; j++) {
                int row = m0 + wr * 64 + m * 16 + lg * 4 + j;
                float v = tanhf(acc[m][n][j] + bias);
                ts[(size_t)row * 512 + col] = f2bf(v);
            }
        }
    }
#undef ISSUE
#undef WRITE
#undef COMPUTE
}

// ---------------------------------------------------------------------------
// GEMM2 + softmax + sigmoid: logits = ts[8192x512] @ W23T^T (130 cols, pad 144)
// one wave per block, 16 rows per wave, 512 blocks (2/CU).
// ---------------------------------------------------------------------------
__global__ __launch_bounds__(64) void gemm2_kernel(
    const u16* __restrict__ ts, const u16* __restrict__ W23T,
    const float* __restrict__ b2, const float* __restrict__ b3,
    float* __restrict__ jw, float* __restrict__ p0)
{
    const int lane = threadIdx.x;
    const int r0 = blockIdx.x * 16;
    const int lr = lane & 15, lg = lane >> 4;

    f32x4 acc[9];
    #pragma unroll
    for (int ct = 0; ct < 9; ct++) { f32x4 z = {0.f,0.f,0.f,0.f}; acc[ct] = z; }

    #pragma unroll 4
    for (int kk = 0; kk < 16; ++kk) {
        int k0 = kk * 32 + lg * 8;
        bf16x8 a = *(const bf16x8*)(ts + (size_t)(r0 + lr) * 512 + k0);
        #pragma unroll
        for (int ct = 0; ct < 9; ct++) {
            bf16x8 bv = *(const bf16x8*)(W23T + (size_t)(ct * 16 + lr) * 512 + k0);
            acc[ct] = __builtin_amdgcn_mfma_f32_16x16x32_bf16(a, bv, acc[ct], 0, 0, 0);
        }
    }

    float b3v = b3[0];
    #pragma unroll
    for (int j = 0; j < 4; j++) {
        int row = r0 + lg * 4 + j;
        float v[9];
        float mx = -1e30f;
        #pragma unroll
        for (int ct = 0; ct < 9; ct++) {
            int col = ct * 16 + lr;
            if (col < 129) { float x = acc[ct][j] + b2[col]; v[ct] = x; mx = fmaxf(mx, x); }
            else v[ct] = -1e30f;
        }
        #pragma unroll
        for (int o = 1; o < 16; o <<= 1) mx = fmaxf(mx, __shfl_xor(mx, o));
        float sum = 0.f;
        #pragma unroll
        for (int ct = 0; ct < 9; ct++) {
            int col = ct * 16 + lr;
            if (col < 129) { float e = expf(v[ct] - mx); v[ct] = e; sum += e; }
        }
        #pragma unroll
        for (int o = 1; o < 16; o <<= 1) sum += __shfl_xor(sum, o);
        float inv = 1.0f / sum;
        #pragma unroll
        for (int ct = 0; ct < 9; ct++) {
            int col = ct * 16 + lr;
            if (col < 129) jw[(size_t)row * 132 + col] = v[ct] * inv;
        }
        if (lr == 1) {  // col 129 = p0 logit
            float pv = acc[8][j] + b3v;
            p0[row] = 1.0f / (1.0f + expf(-pv));
        }
    }
}

// ---------------------------------------------------------------------------
// Recurrence: one block = one batch, 64 threads (1 wave).
// Band preloaded into 64 VGPRs/lane (shifted layout: breg[it] = jw[it][64+c-it]),
// per iter: 16 broadcast ds_read_b128 of atil + 64 FMA + wave reduce + rcp.
// ---------------------------------------------------------------------------
__global__ __launch_bounds__(64) void recur_kernel(
    const float* __restrict__ jw, const float* __restrict__ p0g,
    const float* __restrict__ em, const int* __restrict__ slen,
    float* __restrict__ out)
{
    __shared__ float em_s[128][65];
    __shared__ float atil_s[64];
    const int b = blockIdx.x, c = threadIdx.x;   // c = 0..63

    // band -> registers (coalesced per it: lane c reads consecutive floats)
    float breg[64];
    const float* jwb = jw + (size_t)b * 64 * 132;
    #pragma unroll
    for (int it = 0; it < 64; ++it) breg[it] = jwb[it * 132 + 64 + c - it];

    // emission -> LDS [n][i], pad 65 (conflict-free column reads)
    const float4* eg = (const float4*)(em + (size_t)b * 8192);
    #pragma unroll 4
    for (int i4 = c; i4 < 2048; i4 += 64) {
        float4 v = eg[i4];
        int base = i4 * 4; int n = base >> 6; int ii = base & 63;
        em_s[n][ii] = v.x; em_s[n][ii + 1] = v.y; em_s[n][ii + 2] = v.z; em_s[n][ii + 3] = v.w;
    }
    float p0r = p0g[b * 64 + c];
    const int idx = slen[b] - 1;
    __syncthreads();

    float atil = em_s[c][0] + em_s[c + 64][0];
    atil_s[c] = atil;
    float Lacc = 0.f;   // sum of log2(s_i)
    __syncthreads();

    for (int i = 1; i <= idx; ++i) {
        float em_lo = em_s[c][i];
        float em_hi = em_s[c + 64][i];
        float s0 = 0.f, s1 = 0.f, s2 = 0.f, s3 = 0.f;
        #pragma unroll
        for (int it4 = 0; it4 < 16; ++it4) {
            float4 av = *(const float4*)&atil_s[it4 * 4];   // lane-uniform broadcast
            s0 = fmaf(av.x, breg[it4 * 4 + 0], s0);
            s1 = fmaf(av.y, breg[it4 * 4 + 1], s1);
            s2 = fmaf(av.z, breg[it4 * 4 + 2], s2);
            s3 = fmaf(av.w, breg[it4 * 4 + 3], s3);
        }
        float ulo = ((s0 + s1) + (s2 + s3)) * em_lo;
        float uup = atil * p0r * em_hi;
        float ut = ulo + uup;
        float r = ut;
        #pragma unroll
        for (int o = 1; o < 64; o <<= 1) r += __shfl_xor(r, o);
        Lacc += __log2f(r);
        float inv = __builtin_amdgcn_rcpf(r);
        atil = ut * inv;
        atil_s[c] = atil;
        __syncthreads();   // 1-wave barrier: cheap, orders the LDS write vs next broadcasts
    }
    if (c == 0) out[b] = 1.0f + 0.6931471805599453f * (Lacc + 7.0f * (float)idx);
}

extern "C" void kernel_launch(void* const* d_in, const int* in_sizes, int n_in,
                              void* d_out, int out_size, void* d_ws, size_t ws_size,
                              hipStream_t stream)
{
    const float* Y   = (const float*)d_in[0];
    const float* em  = (const float*)d_in[1];
    const int*   sl  = (const int*)d_in[2];
    const float* W1  = (const float*)d_in[3];
    const float* b1  = (const float*)d_in[4];
    const float* W2  = (const float*)d_in[5];
    const float* b2  = (const float*)d_in[6];
    const float* W3  = (const float*)d_in[7];
    const float* b3  = (const float*)d_in[8];
    float* out = (float*)d_out;
    char* ws = (char*)d_ws;

    __bf16* W1T  = (__bf16*)(ws + OFF_W1T);
    __bf16* W23T = (__bf16*)(ws + OFF_W23T);
    u16*    ts   = (u16*)(ws + OFF_TS);
    float*  jw   = (float*)(ws + OFF_JW);
    float*  p0   = (float*)(ws + OFF_P0);

    prep_kernel<<<2336, 256, 0, stream>>>(W1, W2, W3, W1T, W23T);
    dim3 g1(64, 4);
    gemm1_kernel<<<g1, 512, 0, stream>>>(Y, W1T, b1, ts);
    gemm2_kernel<<<512, 64, 0, stream>>>(ts, (const u16*)W23T, b2, b3, jw, p0);
    recur_kernel<<<128, 64, 0, stream>>>(jw, p0, em, sl, out);
}

// Round 3
// 86.539 us; speedup vs baseline: 1.6227x; 1.1293x over previous
//
#include <hip/hip_runtime.h>
#include <hip/hip_bf16.h>

typedef float f32x4 __attribute__((ext_vector_type(4)));
typedef __bf16 bf16x8 __attribute__((ext_vector_type(8)));
typedef unsigned short u16;

// Problem dims (fixed): B=128, T=64, H=1024, Hu=512, J=129, N=128, I=64, MJW=64
// ws layout
#define OFF_W1T  0u            // 512x1024 bf16 = 1048576 B  (W1T[n][k] = W1[k][n])
#define OFF_W23B 1048576u      // 144x512 bf16 in MFMA-fragment order = 147456 B
#define OFF_TS   1196032u      // 8192x512 bf16 = 8388608 B
#define OFF_JWS  9584640u      // 8192x64 f32 (pre-shifted band) = 2097152 B
#define OFF_P0   11681792u     // 8192 f32 = 32768 B

static __device__ __forceinline__ u16 f2bf(float x) {
    __bf16 h = (__bf16)x;
    return __builtin_bit_cast(u16, h);
}

// ---------------------------------------------------------------------------
// prep: blocks 0..127 = coalesced LDS-tile transpose W1(1024x512 f32)->W1T bf16
//       blocks 128..163 = W2/W3 -> W23B in MFMA fragment order:
//         W23B[((kk*9+ct)*64 + lg*16+lr)*8 + j] = B[n=ct*16+lr][k=kk*32+lg*8+j]
// ---------------------------------------------------------------------------
__global__ __launch_bounds__(256) void prep_kernel(
    const float* __restrict__ W1, const float* __restrict__ W2,
    const float* __restrict__ W3,
    __bf16* __restrict__ W1T, __bf16* __restrict__ W23B)
{
    const int t = threadIdx.x;
    if (blockIdx.x < 128) {
        __shared__ __bf16 lds_t[64][72];
        const int kt = blockIdx.x >> 3, nt = blockIdx.x & 7;
        const int k0 = kt * 64, n0 = nt * 64;
        // load 64x64 f32 tile coalesced, convert to bf16 in LDS
        {
            const int kr = t >> 2, c0 = (t & 3) * 16;
            const float* src = W1 + (size_t)(k0 + kr) * 512 + n0 + c0;
            #pragma unroll
            for (int q = 0; q < 4; ++q) {
                float4 v = *(const float4*)(src + q * 4);
                lds_t[kr][c0 + q * 4 + 0] = (__bf16)v.x;
                lds_t[kr][c0 + q * 4 + 1] = (__bf16)v.y;
                lds_t[kr][c0 + q * 4 + 2] = (__bf16)v.z;
                lds_t[kr][c0 + q * 4 + 3] = (__bf16)v.w;
            }
        }
        __syncthreads();
        // write transposed, coalesced 16B stores
        {
            const int nr = t >> 2, kc = (t & 3) * 16;
            bf16x8 o0, o1;
            #pragma unroll
            for (int j = 0; j < 8; ++j) o0[j] = lds_t[kc + j][nr];
            #pragma unroll
            for (int j = 0; j < 8; ++j) o1[j] = lds_t[kc + 8 + j][nr];
            __bf16* dst = W1T + (size_t)(n0 + nr) * 1024 + k0 + kc;
            *(bf16x8*)(dst)     = o0;
            *(bf16x8*)(dst + 8) = o1;
        }
    } else {
        int g = (blockIdx.x - 128) * 256 + t;   // 0..9215
        if (g < 9216) {
            int n = g >> 6;            // 0..143
            int k8 = (g & 63) * 8;     // 0,8,..,504
            bf16x8 v;
            #pragma unroll
            for (int j = 0; j < 8; ++j) {
                int k = k8 + j;
                float x = 0.0f;
                if (n < 129) x = W2[(size_t)k * 129 + n];
                else if (n == 129) x = W3[k];
                v[j] = (__bf16)x;
            }
            int kk = k8 >> 5, lg = (k8 >> 3) & 3, ct = n >> 4, lr = n & 15;
            W23B[(((size_t)(kk * 9 + ct)) * 64 + lg * 16 + lr) * 8] = v[0];
            *(bf16x8*)&W23B[(((size_t)(kk * 9 + ct)) * 64 + lg * 16 + lr) * 8] = v;
        }
    }
}

// ---------------------------------------------------------------------------
// GEMM1: ts = tanh(Y[8192x1024] @ W1[1024x512] + b1), bf16 MFMA 16x16x32
// 128x128 tile, BK=64, 512 threads (8 waves 2x4), dbuf swizzled LDS,
// RAW s_barrier (no vmcnt drain) so prefetch loads stay in flight.
// ---------------------------------------------------------------------------
struct Stage {
    float4 a0, a1, a2, a3;   // 16 f32 of Y
    uint4  b0, b1;           // 16 bf16 of W1T
};

__global__ __launch_bounds__(512) void gemm1_kernel(
    const float* __restrict__ Y, const __bf16* __restrict__ W1T,
    const float* __restrict__ b1, u16* __restrict__ ts)
{
    __shared__ __bf16 As[2][128 * 64];
    __shared__ __bf16 Bs[2][128 * 64];
    const int tid = threadIdx.x;
    const int m0 = blockIdx.x * 128, n0 = blockIdx.y * 128;
    const int wid = tid >> 6, lane = tid & 63;
    const int wr = wid >> 2, wc = wid & 3;          // 2 x 4 waves, wave tile 64x32
    const int lr = lane & 15, lg = lane >> 4;

    const int ra = tid >> 2;             // staging row 0..127
    const int kc = (tid & 3) * 16;       // staging k-chunk 0/16/32/48
    const int esw = ((ra & 7) << 3);     // XOR swizzle
    const int e0 = kc ^ esw;
    const int e1 = (kc + 8) ^ esw;

    const float*  ya = Y   + (size_t)(m0 + ra) * 1024 + kc;
    const __bf16* wb = W1T + (size_t)(n0 + ra) * 1024 + kc;

    f32x4 acc[4][2];
    #pragma unroll
    for (int m = 0; m < 4; m++)
        #pragma unroll
        for (int n = 0; n < 2; n++) { f32x4 z = {0.f,0.f,0.f,0.f}; acc[m][n] = z; }

#define ISSUE(S, kt) do { \
    const float4* yp = (const float4*)(ya + (kt) * 64); \
    (S).a0 = yp[0]; (S).a1 = yp[1]; (S).a2 = yp[2]; (S).a3 = yp[3]; \
    const uint4* wp = (const uint4*)(wb + (kt) * 64); \
    (S).b0 = wp[0]; (S).b1 = wp[1]; \
} while (0)

#define WRITE(S, buf) do { \
    bf16x8 pa0, pa1; \
    pa0[0]=(__bf16)(S).a0.x; pa0[1]=(__bf16)(S).a0.y; pa0[2]=(__bf16)(S).a0.z; pa0[3]=(__bf16)(S).a0.w; \
    pa0[4]=(__bf16)(S).a1.x; pa0[5]=(__bf16)(S).a1.y; pa0[6]=(__bf16)(S).a1.z; pa0[7]=(__bf16)(S).a1.w; \
    pa1[0]=(__bf16)(S).a2.x; pa1[1]=(__bf16)(S).a2.y; pa1[2]=(__bf16)(S).a2.z; pa1[3]=(__bf16)(S).a2.w; \
    pa1[4]=(__bf16)(S).a3.x; pa1[5]=(__bf16)(S).a3.y; pa1[6]=(__bf16)(S).a3.z; pa1[7]=(__bf16)(S).a3.w; \
    *(bf16x8*)&As[buf][ra * 64 + e0] = pa0; \
    *(bf16x8*)&As[buf][ra * 64 + e1] = pa1; \
    *(uint4*)&Bs[buf][ra * 64 + e0] = (S).b0; \
    *(uint4*)&Bs[buf][ra * 64 + e1] = (S).b1; \
} while (0)

#define BARRIER() do { \
    asm volatile("s_waitcnt lgkmcnt(0)" ::: "memory"); \
    __builtin_amdgcn_s_barrier(); \
} while (0)

#define COMPUTE(buf) do { \
    const int swl = (lr & 7) << 3; \
    _Pragma("unroll") \
    for (int ks = 0; ks < 2; ++ks) { \
        const int eoff = (ks * 32 + lg * 8) ^ swl; \
        bf16x8 af[4], bfr[2]; \
        _Pragma("unroll") \
        for (int m = 0; m < 4; ++m) af[m] = *(const bf16x8*)&As[buf][(wr * 64 + m * 16 + lr) * 64 + eoff]; \
        _Pragma("unroll") \
        for (int n = 0; n < 2; ++n) bfr[n] = *(const bf16x8*)&Bs[buf][(wc * 32 + n * 16 + lr) * 64 + eoff]; \
        __builtin_amdgcn_s_setprio(1); \
        _Pragma("unroll") \
        for (int m = 0; m < 4; ++m) \
            _Pragma("unroll") \
            for (int n = 0; n < 2; ++n) \
                acc[m][n] = __builtin_amdgcn_mfma_f32_16x16x32_bf16(af[m], bfr[n], acc[m][n], 0, 0, 0); \
        __builtin_amdgcn_s_setprio(0); \
    } \
} while (0)

    Stage SA, SB;
    ISSUE(SA, 0);
    #pragma unroll 1
    for (int kt = 0; kt < 16; kt += 2) {
        ISSUE(SB, kt + 1);      // stays in flight across the raw barrier
        WRITE(SA, 0);           // waits only SA's loads (counted vmcnt)
        BARRIER();
        COMPUTE(0);
        if (kt + 2 < 16) ISSUE(SA, kt + 2);
        WRITE(SB, 1);
        BARRIER();
        COMPUTE(1);
    }

    // epilogue: bias + tanh + bf16 store
    #pragma unroll
    for (int m = 0; m < 4; m++) {
        #pragma unroll
        for (int n = 0; n < 2; n++) {
            int col = n0 + wc * 32 + n * 16 + lr;
            float bias = b1[col];
            #pragma unroll
            for (int j = 0; j < 4; j++) {
                int row = m0 + wr * 64 + m * 16 + lg * 4 + j;
                float v = tanhf(acc[m][n][j] + bias);
                ts[(size_t)row * 512 + col] = f2bf(v);
            }
        }
    }
#undef ISSUE
#undef WRITE
#undef BARRIER
#undef COMPUTE
}

// ---------------------------------------------------------------------------
// GEMM2 + softmax + sigmoid. 256 blocks x 128 thr (2 waves, 16 rows/wave).
// B-operand from W23B in fragment order (fully coalesced 16B/lane loads).
// Writes the PRE-SHIFTED band jwS[row][c] = softmax_row[64 + c - (row&63)]
// (the only entries the recurrence reads), plus p0.
// ---------------------------------------------------------------------------
__global__ __launch_bounds__(128) void gemm2_kernel(
    const u16* __restrict__ ts, const u16* __restrict__ W23B,
    const float* __restrict__ b2, const float* __restrict__ b3,
    float* __restrict__ jwS, float* __restrict__ p0)
{
    const int tid = threadIdx.x;
    const int lane = tid & 63, w = tid >> 6;
    const int r0 = blockIdx.x * 32 + w * 16;
    const int lr = lane & 15, lg = lane >> 4;

    f32x4 acc[9];
    #pragma unroll
    for (int ct = 0; ct < 9; ct++) { f32x4 z = {0.f,0.f,0.f,0.f}; acc[ct] = z; }

    #pragma unroll 4
    for (int kk = 0; kk < 16; ++kk) {
        bf16x8 a = *(const bf16x8*)(ts + (size_t)(r0 + lr) * 512 + kk * 32 + lg * 8);
        #pragma unroll
        for (int ct = 0; ct < 9; ct++) {
            bf16x8 bv = *(const bf16x8*)(W23B + ((size_t)(kk * 9 + ct) * 64 + lane) * 8);
            acc[ct] = __builtin_amdgcn_mfma_f32_16x16x32_bf16(a, bv, acc[ct], 0, 0, 0);
        }
    }

    float b3v = b3[0];
    #pragma unroll
    for (int j = 0; j < 4; j++) {
        int row = r0 + lg * 4 + j;
        int trow = row & 63;
        float v[9];
        float mx = -1e30f;
        #pragma unroll
        for (int ct = 0; ct < 9; ct++) {
            int col = ct * 16 + lr;
            if (col < 129) { float x = acc[ct][j] + b2[col]; v[ct] = x; mx = fmaxf(mx, x); }
            else v[ct] = -1e30f;
        }
        #pragma unroll
        for (int o = 1; o < 16; o <<= 1) mx = fmaxf(mx, __shfl_xor(mx, o));
        float sum = 0.f;
        #pragma unroll
        for (int ct = 0; ct < 9; ct++) {
            int col = ct * 16 + lr;
            if (col < 129) { float e = expf(v[ct] - mx); v[ct] = e; sum += e; }
        }
        #pragma unroll
        for (int o = 1; o < 16; o <<= 1) sum += __shfl_xor(sum, o);
        float inv = 1.0f / sum;
        #pragma unroll
        for (int ct = 0; ct < 9; ct++) {
            int col = ct * 16 + lr;
            int cc = col - 64 + trow;
            if (col < 129 && cc >= 0 && cc < 64)
                jwS[(size_t)row * 64 + cc] = v[ct] * inv;
        }
        if (lr == 1) {  // col 129 = p0 logit
            float pv = acc[8][j] + b3v;
            p0[row] = 1.0f / (1.0f + expf(-pv));
        }
    }
}

// ---------------------------------------------------------------------------
// Recurrence: one block = one batch, 64 threads (1 wave).
// Pre-shifted band in 64 VGPRs/lane; deferred normalization (every 4 iters):
// matvec is scale-invariant, sum of log2 telescopes.
// ---------------------------------------------------------------------------
__global__ __launch_bounds__(64) void recur_kernel(
    const float* __restrict__ jwS, const float* __restrict__ p0g,
    const float* __restrict__ em, const int* __restrict__ slen,
    float* __restrict__ out)
{
    __shared__ float em_s[128][65];
    __shared__ float atil_s[64];
    const int b = blockIdx.x, c = threadIdx.x;   // c = 0..63

    float breg[64];
    const float* jwb = jwS + (size_t)b * 64 * 64;
    #pragma unroll
    for (int it = 0; it < 64; ++it) breg[it] = jwb[it * 64 + c];   // coalesced

    const float4* eg = (const float4*)(em + (size_t)b * 8192);
    #pragma unroll 4
    for (int i4 = c; i4 < 2048; i4 += 64) {
        float4 v = eg[i4];
        int base = i4 * 4; int n = base >> 6; int ii = base & 63;
        em_s[n][ii] = v.x; em_s[n][ii + 1] = v.y; em_s[n][ii + 2] = v.z; em_s[n][ii + 3] = v.w;
    }
    float p0r = p0g[b * 64 + c];
    const int idx = slen[b] - 1;
    __syncthreads();

    float atil = em_s[c][0] + em_s[c + 64][0];
    atil_s[c] = atil;
    float Lacc = 0.f;   // sum of log2(r) at rescale points
    __syncthreads();

    for (int i = 1; i <= idx; ++i) {
        float s0 = 0.f, s1 = 0.f, s2 = 0.f, s3 = 0.f;
        #pragma unroll
        for (int it4 = 0; it4 < 16; ++it4) {
            float4 av = *(const float4*)&atil_s[it4 * 4];   // lane-uniform broadcast
            s0 = fmaf(av.x, breg[it4 * 4 + 0], s0);
            s1 = fmaf(av.y, breg[it4 * 4 + 1], s1);
            s2 = fmaf(av.z, breg[it4 * 4 + 2], s2);
            s3 = fmaf(av.w, breg[it4 * 4 + 3], s3);
        }
        float ut = ((s0 + s1) + (s2 + s3)) * em_s[c][i]
                 + atil * p0r * em_s[c + 64][i];
        if (((i & 3) == 0) || (i == idx)) {
            float r = ut;
            #pragma unroll
            for (int o = 1; o < 64; o <<= 1) r += __shfl_xor(r, o);
            Lacc += __log2f(r);
            ut *= __builtin_amdgcn_rcpf(r);
        }
        atil = ut;
        atil_s[c] = ut;
        __syncthreads();
    }
    if (c == 0) out[b] = 1.0f + 0.6931471805599453f * (Lacc + 7.0f * (float)idx);
}

extern "C" void kernel_launch(void* const* d_in, const int* in_sizes, int n_in,
                              void* d_out, int out_size, void* d_ws, size_t ws_size,
                              hipStream_t stream)
{
    const float* Y   = (const float*)d_in[0];
    const float* em  = (const float*)d_in[1];
    const int*   sl  = (const int*)d_in[2];
    const float* W1  = (const float*)d_in[3];
    const float* b1  = (const float*)d_in[4];
    const float* W2  = (const float*)d_in[5];
    const float* b2  = (const float*)d_in[6];
    const float* W3  = (const float*)d_in[7];
    const float* b3  = (const float*)d_in[8];
    float* out = (float*)d_out;
    char* ws = (char*)d_ws;

    __bf16* W1T  = (__bf16*)(ws + OFF_W1T);
    __bf16* W23B = (__bf16*)(ws + OFF_W23B);
    u16*    ts   = (u16*)(ws + OFF_TS);
    float*  jwS  = (float*)(ws + OFF_JWS);
    float*  p0   = (float*)(ws + OFF_P0);

    prep_kernel<<<164, 256, 0, stream>>>(W1, W2, W3, W1T, W23B);
    dim3 g1(64, 4);
    gemm1_kernel<<<g1, 512, 0, stream>>>(Y, W1T, b1, ts);
    gemm2_kernel<<<256, 128, 0, stream>>>(ts, (const u16*)W23B, b2, b3, jwS, p0);
    recur_kernel<<<128, 64, 0, stream>>>(jwS, p0, em, sl, out);
}